// Round 8
// baseline (132.363 us; speedup 1.0000x reference)
//
#include <hip/hip_runtime.h>
#include <math.h>

// LocalAttention: B=2, T=2048, C=512, WINDOW=32
#define BB 2
#define TT 2048
#define CC 512
#define WIN 32
#define WSZ 63            // 2*WIN-1
#define MM (BB * TT)      // 4096
#define QKLD 1024         // qkv intermediate row stride (Q | K only)

typedef __attribute__((ext_vector_type(8))) short short8;
typedef __attribute__((ext_vector_type(4))) float floatx4;

__device__ inline unsigned short bf16_rn(float f) {
  unsigned u = __builtin_bit_cast(unsigned, f);
  u += 0x7fff + ((u >> 16) & 1);
  return (unsigned short)(u >> 16);
}
__device__ inline unsigned pack_bf16x2(float lo, float hi) {
  return (unsigned)bf16_rn(lo) | ((unsigned)bf16_rn(hi) << 16);
}

// ---------------------------------------------------------------------------
// Convert x fp32 -> bf16. 8 elems/thread, 1024 blocks.
// ---------------------------------------------------------------------------
#define NX (MM * CC)   // 2097152

__global__ __launch_bounds__(256) void convert_x(
    const float* __restrict__ x, ushort* __restrict__ xb) {
  const size_t e = ((size_t)blockIdx.x * 256 + threadIdx.x) * 8;
  float4 v0 = ((const float4*)(x + e))[0];
  float4 v1 = ((const float4*)(x + e))[1];
  uint4 o;
  o.x = pack_bf16x2(v0.x, v0.y);
  o.y = pack_bf16x2(v0.z, v0.w);
  o.z = pack_bf16x2(v1.x, v1.y);
  o.w = pack_bf16x2(v1.z, v1.w);
  *(uint4*)(xb + e) = o;
}

// ---------------------------------------------------------------------------
// Barrier-light NT GEMM, BM=64 x BN=64, K=512. Grid (N/64, M/64).
// B is fp32 (weights), converted to bf16 during LDS staging (redundant per
// m-block but VALU-cheap; removes the separate weight-convert pass).
// A fragments direct from global (bf16, L1/L2-hot). 4 waves x 16 m-rows.
// 3 barriers per block; 4 blocks/CU (33.8 KB LDS) -> 16 waves/CU.
// V path (VT!=nullptr && n0>=1024): tile -> bias -> bf16 -> LDS transpose ->
// coalesced VT[n][m] row writes.
// ---------------------------------------------------------------------------
#define PSTR 264   // B-panel k-stride (elems); 528B rows -> spread banks
#define VSTR 80    // V-transpose m-stride (elems); 160B rows

template <typename OT>
__global__ __launch_bounds__(256) void gemm_panel(
    const ushort* __restrict__ A, const float* __restrict__ Bf,
    const float* __restrict__ bias, OT* __restrict__ C, int ldC,
    ushort* __restrict__ VT, int M) {
  __shared__ __align__(16) ushort Bs[64 * PSTR];  // 33792 B

  const int tid = threadIdx.x;
  const int lane = tid & 63;
  const int wave = tid >> 6;
  const int m0 = blockIdx.y * 64;
  const int n0 = blockIdx.x * 64;
  const int mlane = lane & 15, quad = lane >> 4;

  floatx4 acc[4];
#pragma unroll
  for (int j = 0; j < 4; ++j) acc[j] = (floatx4){0.f, 0.f, 0.f, 0.f};

  const ushort* arow = A + (size_t)(m0 + wave * 16 + mlane) * CC;

  for (int h = 0; h < 2; ++h) {
    if (h) __syncthreads();
    // stage B panel half: 64 rows x 256 k, fp32 -> bf16
#pragma unroll
    for (int i = 0; i < 8; ++i) {
      const int idx = tid + 256 * i;
      const int r = idx >> 5, kc = (idx & 31) * 8;
      const float* src = Bf + (size_t)(n0 + r) * CC + h * 256 + kc;
      float4 v0 = ((const float4*)src)[0];
      float4 v1 = ((const float4*)src)[1];
      uint4 o;
      o.x = pack_bf16x2(v0.x, v0.y);
      o.y = pack_bf16x2(v0.z, v0.w);
      o.z = pack_bf16x2(v1.x, v1.y);
      o.w = pack_bf16x2(v1.z, v1.w);
      *(uint4*)(&Bs[r * PSTR + kc]) = o;
    }
    __syncthreads();
#pragma unroll
    for (int ks = 0; ks < 8; ++ks) {
      short8 af = *(const short8*)(arow + h * 256 + ks * 32 + quad * 8);
#pragma unroll
      for (int ni = 0; ni < 4; ++ni) {
        short8 bfr = *(const short8*)(&Bs[(ni * 16 + mlane) * PSTR + ks * 32 + quad * 8]);
        acc[ni] = __builtin_amdgcn_mfma_f32_16x16x32_bf16(af, bfr, acc[ni], 0, 0, 0);
      }
    }
  }

  // epilogue: D row = quad*4 + r (m), col = mlane (n)
  const bool vpath = (VT != nullptr) && (n0 >= 1024);
  if (!vpath) {
    const int mbase = m0 + wave * 16 + quad * 4;
#pragma unroll
    for (int ni = 0; ni < 4; ++ni) {
      const int n = n0 + ni * 16 + mlane;
      const float bn = bias[n];
#pragma unroll
      for (int r = 0; r < 4; ++r) {
        float val = acc[ni][r] + bn;
        if constexpr (sizeof(OT) == 2)
          ((ushort*)C)[(size_t)(mbase + r) * ldC + n] = bf16_rn(val);
        else
          ((float*)C)[(size_t)(mbase + r) * ldC + n] = val;
      }
    }
  } else {
    ushort* Vt = Bs;  // alias; 64 x VSTR = 10240 B
    __syncthreads();
    const int m_l = wave * 16 + quad * 4;
#pragma unroll
    for (int ni = 0; ni < 4; ++ni) {
      const int n_l = ni * 16 + mlane;
      const float bn = bias[n0 + n_l];
      ushort4 pk;
      pk.x = bf16_rn(acc[ni][0] + bn);
      pk.y = bf16_rn(acc[ni][1] + bn);
      pk.z = bf16_rn(acc[ni][2] + bn);
      pk.w = bf16_rn(acc[ni][3] + bn);
      *(ushort4*)(&Vt[n_l * VSTR + m_l]) = pk;
    }
    __syncthreads();
#pragma unroll
    for (int i = 0; i < 2; ++i) {  // 64 rows x 8 uint4
      const int idx = tid + 256 * i;
      const int n_l = idx >> 3, mo = (idx & 7) * 8;
      *(uint4*)(VT + (size_t)(n0 - 1024 + n_l) * M + m0 + mo) =
          *(const uint4*)(&Vt[n_l * VSTR + mo]);
    }
  }
}

// ---------------------------------------------------------------------------
// LDS-free MFMA banded attention. Block = 8 tokens, grid 512, 4 waves.
// qkv rows are Q|K (stride QKLD=1024). Dual even/odd MFMA chains halve the
// serial-accumulation latency; P fragments hoisted out of the PV loop.
// OOB reads fault-safe via ws guards; garbage lands in masked/P=0 positions.
// ---------------------------------------------------------------------------
#define ATILE 8
#define SLD 84    // S row stride (floats)
#define PLD 104   // P row stride (ushorts), odd granules -> conflict-free

__global__ __launch_bounds__(256) void attn_mfma(
    const ushort* __restrict__ qkv, const ushort* __restrict__ vT,
    ushort* __restrict__ out) {
  __shared__ __align__(16) float s_s[16 * SLD];
  __shared__ __align__(16) ushort p_s[16 * PLD];

  const int tid = threadIdx.x;
  const int wave = tid >> 6, lane = tid & 63;
  const int mlane = lane & 15, quad = lane >> 4;
  const int bt0 = blockIdx.x * ATILE;
  const int b = bt0 / TT, t0 = bt0 % TT;
  const ushort* qbase = qkv + (size_t)b * TT * QKLD;

  // ---- scores: S[16][80] = Q.K^T, direct-global fragments, dual chains ----
  const ushort* qrow  = qbase + (ptrdiff_t)(t0 + mlane) * QKLD;
  const ushort* krow0 = qbase + (ptrdiff_t)(t0 - 32 + wave * 16 + mlane) * QKLD + CC;
  const ushort* krow1 = qbase + (ptrdiff_t)(t0 - 32 + 64 + mlane) * QKLD + CC;
  floatx4 s0a = (floatx4){0.f, 0.f, 0.f, 0.f}, s0b = s0a;
  floatx4 s1a = s0a, s1b = s0a;
#pragma unroll
  for (int ks = 0; ks < 16; ++ks) {
    short8 a  = *(const short8*)(qrow + ks * 32 + quad * 8);
    short8 b0 = *(const short8*)(krow0 + ks * 32 + quad * 8);
    if (ks & 1) s0b = __builtin_amdgcn_mfma_f32_16x16x32_bf16(a, b0, s0b, 0, 0, 0);
    else        s0a = __builtin_amdgcn_mfma_f32_16x16x32_bf16(a, b0, s0a, 0, 0, 0);
    if (wave == 0) {  // wave-uniform: wave0 also owns col-tile 4
      short8 b1 = *(const short8*)(krow1 + ks * 32 + quad * 8);
      if (ks & 1) s1b = __builtin_amdgcn_mfma_f32_16x16x32_bf16(a, b1, s1b, 0, 0, 0);
      else        s1a = __builtin_amdgcn_mfma_f32_16x16x32_bf16(a, b1, s1a, 0, 0, 0);
    }
  }

#pragma unroll
  for (int r = 0; r < 4; ++r)
    s_s[(quad * 4 + r) * SLD + wave * 16 + mlane] = s0a[r] + s0b[r];
  if (wave == 0) {
#pragma unroll
    for (int r = 0; r < 4; ++r)
      s_s[(quad * 4 + r) * SLD + 64 + mlane] = s1a[r] + s1b[r];
  }
  __syncthreads();

  // ---- softmax: 16 rows x 16 lanes, 5 cols each; mask j = r-1-row ----
  {
    const int row = tid >> 4, li = tid & 15;
    const float inv_scale = 0.044194173824159216f;  // 512^-0.5
    float e[5];
    float mx = -INFINITY;
#pragma unroll
    for (int i = 0; i < 5; ++i) {
      const int r = li + 16 * i;
      const int j = r - 1 - row;
      const int src = t0 - 32 + r;
      const bool valid = (j >= 0) && (j < WSZ) && (src >= 0) && (src < TT);
      e[i] = valid ? s_s[row * SLD + r] * inv_scale : -INFINITY;
      mx = fmaxf(mx, e[i]);
    }
    mx = fmaxf(mx, __shfl_xor(mx, 1)); mx = fmaxf(mx, __shfl_xor(mx, 2));
    mx = fmaxf(mx, __shfl_xor(mx, 4)); mx = fmaxf(mx, __shfl_xor(mx, 8));
    float sum = 0.f;
#pragma unroll
    for (int i = 0; i < 5; ++i) {
      e[i] = (e[i] == -INFINITY) ? 0.f : __expf(e[i] - mx);
      sum += e[i];
    }
    sum += __shfl_xor(sum, 1); sum += __shfl_xor(sum, 2);
    sum += __shfl_xor(sum, 4); sum += __shfl_xor(sum, 8);
    const float rs = 1.f / sum;
#pragma unroll
    for (int i = 0; i < 5; ++i)
      p_s[row * PLD + li + 16 * i] = bf16_rn(e[i] * rs);
    if (li < 8) {  // zero k-pad cols 80..103 (PV k-extent is 96)
      p_s[row * PLD + 80 + li] = 0;
      p_s[row * PLD + 88 + li] = 0;
      p_s[row * PLD + 96 + li] = 0;
    }
  }
  __syncthreads();

  // ---- PV: Out[16][512] = P.V, V direct from vT[c][m]; P frags hoisted ----
  const ptrdiff_t mcol0 = (ptrdiff_t)b * TT + t0 - 32;
  short8 pa[3];
#pragma unroll
  for (int ks = 0; ks < 3; ++ks)
    pa[ks] = *(const short8*)(&p_s[mlane * PLD + ks * 32 + quad * 8]);
#pragma unroll 2
  for (int nt8 = 0; nt8 < 8; ++nt8) {
    const int nt = wave * 8 + nt8;
    const ushort* vrow = vT + (ptrdiff_t)(nt * 16 + mlane) * MM + mcol0;
    floatx4 o = (floatx4){0.f, 0.f, 0.f, 0.f};
#pragma unroll
    for (int ks = 0; ks < 3; ++ks) {
      short8 bv = *(const short8*)(vrow + ks * 32 + quad * 8);
      o = __builtin_amdgcn_mfma_f32_16x16x32_bf16(pa[ks], bv, o, 0, 0, 0);
    }
    if (quad < 2) {  // D rows 0..7 are the real tokens
#pragma unroll
      for (int r = 0; r < 4; ++r)
        out[(size_t)(bt0 + quad * 4 + r) * CC + nt * 16 + mlane] = bf16_rn(o[r]);
    }
  }
}

// ---------------------------------------------------------------------------
extern "C" void kernel_launch(void* const* d_in, const int* in_sizes, int n_in,
                              void* d_out, int out_size, void* d_ws, size_t ws_size,
                              hipStream_t stream) {
  const float* x      = (const float*)d_in[0];
  const float* w_qkv  = (const float*)d_in[1];
  const float* b_qkv  = (const float*)d_in[2];
  const float* w_proj = (const float*)d_in[3];
  const float* b_proj = (const float*)d_in[4];
  float* outp = (float*)d_out;

  // ws layout (ushorts). 256 KB front guard absorbs attn's src<0 reads;
  // attn buffer right after qkv absorbs src>=TT overruns. vT has 64-elem guards.
  ushort* base  = (ushort*)d_ws;
  ushort* qkv   = base + 131072;                   // MM x QKLD (Q | K)
  ushort* attn  = qkv + (size_t)MM * QKLD;         // MM x 512
  ushort* xb    = attn + (size_t)MM * CC;          // MM x 512
  ushort* vTg   = xb + (size_t)NX;                 // guard(64) + 512 x 4096 + guard(64)
  ushort* vT    = vTg + 64;

  // 0) convert x fp32 -> bf16
  convert_x<<<NX / (256 * 8), 256, 0, stream>>>(x, xb);
  // 1) qkv = x @ w_qkv.T + b_qkv -> Q,K rows (ld 1024); V transposed to vT
  {
    dim3 grid((3 * CC) / 64, MM / 64);  // 24 x 64 = 1536 blocks
    gemm_panel<ushort><<<grid, 256, 0, stream>>>(xb, w_qkv, b_qkv, qkv, QKLD, vT, MM);
  }
  // 2) banded attention (bf16 -> bf16), LDS-free MFMA
  attn_mfma<<<MM / ATILE, 256, 0, stream>>>(qkv, vT, attn);
  // 3) out = attn @ w_proj.T + b_proj -> fp32
  {
    dim3 grid(CC / 64, MM / 64);  // 8 x 64 = 512 blocks
    gemm_panel<float><<<grid, 256, 0, stream>>>(attn, w_proj, b_proj, outp, CC, nullptr, MM);
  }
}